// Round 4
// baseline (231.324 us; speedup 1.0000x reference)
//
#include <hip/hip_runtime.h>

#define N_ROWS 32768
#define D_IN 320
#define CB 16
#define N_BOOKS 8192

typedef __attribute__((ext_vector_type(8))) short bf16x8;
typedef __attribute__((ext_vector_type(4))) float f32x4;
#define MFMA __builtin_amdgcn_mfma_f32_16x16x32_bf16

__device__ __forceinline__ unsigned short bf16rn(float f) {
  unsigned u = __float_as_uint(f);
  u += 0x7fffu + ((u >> 16) & 1u);
  return (unsigned short)(u >> 16);
}
__device__ __forceinline__ float bf16tof(unsigned short h) {
  return __uint_as_float(((unsigned)h) << 16);
}

// ---------------- Kernel 1: targets = X @ W^T via bf16 3-split MFMA ----------------
// fp64 accumulation across chunks AND across split-groups within a chunk:
// group1 = x1w1 ; group2 = x2w1 + x1w2 ; group3 = x3w1 + x1w3 + x2w2.
// Each group's fp32 MFMA partial is flushed into fp64 -> t error ~1e-7 rel.
__global__ __launch_bounds__(256, 2) void proj_kernel(const float* __restrict__ x,
                                                      const float* __restrict__ w,
                                                      float* __restrict__ targets) {
  __shared__ __align__(16) short wfrag[3][10][64][8];  // 30720 B
  __shared__ __align__(16) float xs[2][64 * 36];       // 18432 B
  const int tid = threadIdx.x;
  const int lane = tid & 63;
  const int wv = tid >> 6;

  for (int i = tid; i < D_IN * CB; i += 256) {
    int d = i >> 4, o = i & 15;
    float f = w[o * D_IN + d];
    unsigned short h1 = bf16rn(f);
    float r1 = f - bf16tof(h1);
    unsigned short h2 = bf16rn(r1);
    float r2 = r1 - bf16tof(h2);
    unsigned short h3 = bf16rn(r2);
    int c = d >> 5, qq = (d >> 3) & 3, pos = d & 7;
    int ln = qq * 16 + o;
    wfrag[0][c][ln][pos] = (short)h1;
    wfrag[1][c][ln][pos] = (short)h2;
    wfrag[2][c][ln][pos] = (short)h3;
  }

  const float* xblk = x + (size_t)blockIdx.x * 64 * D_IN;
  {
    int row = tid >> 2, k0 = (tid & 3) * 8;
    float4 v0 = *(const float4*)(xblk + row * D_IN + k0);
    float4 v1 = *(const float4*)(xblk + row * D_IN + k0 + 4);
    *(float4*)&xs[0][row * 36 + k0] = v0;
    *(float4*)&xs[0][row * 36 + k0 + 4] = v1;
  }
  __syncthreads();

  const int m = lane & 15, q = lane >> 4;
  double dacc[4] = {0.0, 0.0, 0.0, 0.0};
  for (int c = 0; c < 10; c++) {
    const int buf = c & 1;
    if (c < 9) {
      int row = tid >> 2, k0 = (tid & 3) * 8;
      float4 v0 = *(const float4*)(xblk + row * D_IN + (c + 1) * 32 + k0);
      float4 v1 = *(const float4*)(xblk + row * D_IN + (c + 1) * 32 + k0 + 4);
      *(float4*)&xs[buf ^ 1][row * 36 + k0] = v0;
      *(float4*)&xs[buf ^ 1][row * 36 + k0 + 4] = v1;
    }
    const float* xp = &xs[buf][(wv * 16 + m) * 36 + q * 8];
    float4 xa = *(const float4*)xp;
    float4 xb = *(const float4*)(xp + 4);
    float xe[8] = {xa.x, xa.y, xa.z, xa.w, xb.x, xb.y, xb.z, xb.w};
    bf16x8 a1, a2, a3;
#pragma unroll
    for (int j = 0; j < 8; j++) {
      unsigned short h1 = bf16rn(xe[j]);
      float r1 = xe[j] - bf16tof(h1);
      unsigned short h2 = bf16rn(r1);
      float r2 = r1 - bf16tof(h2);
      unsigned short h3 = bf16rn(r2);
      a1[j] = (short)h1; a2[j] = (short)h2; a3[j] = (short)h3;
    }
    bf16x8 b1 = *(const bf16x8*)wfrag[0][c][lane];
    bf16x8 b2 = *(const bf16x8*)wfrag[1][c][lane];
    bf16x8 b3 = *(const bf16x8*)wfrag[2][c][lane];
    f32x4 g = {0.f, 0.f, 0.f, 0.f};
    g = MFMA(a1, b1, g, 0, 0, 0);  // group 1 (O(1) terms)
#pragma unroll
    for (int r = 0; r < 4; r++) dacc[r] += (double)g[r];
    g = (f32x4){0.f, 0.f, 0.f, 0.f};
    g = MFMA(a2, b1, g, 0, 0, 0);  // group 2 (O(2^-8))
    g = MFMA(a1, b2, g, 0, 0, 0);
#pragma unroll
    for (int r = 0; r < 4; r++) dacc[r] += (double)g[r];
    g = (f32x4){0.f, 0.f, 0.f, 0.f};
    g = MFMA(a3, b1, g, 0, 0, 0);  // group 3 (O(2^-16))
    g = MFMA(a1, b3, g, 0, 0, 0);
    g = MFMA(a2, b2, g, 0, 0, 0);
#pragma unroll
    for (int r = 0; r < 4; r++) dacc[r] += (double)g[r];
    __syncthreads();
  }
  const int growbase = blockIdx.x * 64 + wv * 16 + q * 4;
#pragma unroll
  for (int r = 0; r < 4; r++) targets[(size_t)(growbase + r) * CB + m] = (float)dacc[r];
}

// ---------------- Kernel 2: approx scores via MFMA + per-chunk top-2 ----------------
// argmin d2 == argmax m = t.c - 0.5||c||^2. Track (s1, s2, i1) per row per chunk.
// block = 4 waves, 256 rows (wave: 4 row-tiles); chunk = 1024 books = 4 LDS sub-stages of 256.
#define SC_RG 128  // row groups of 256 rows
#define SC_NCH 8   // book chunks of 1024

__global__ __launch_bounds__(256, 2) void score_kernel(const float* __restrict__ targets,
                                                       const float* __restrict__ codebook,
                                                       float4* __restrict__ cand) {
  __shared__ __align__(16) char smraw[50176];
  float* tst = (float*)smraw;                             // phase 1-2: 256 rows x stride 20 = 20480 B
  short (*bfr)[16][64][8] = (short (*)[16][64][8])smraw;  // phase 3-4: 49152 B (aliases tst)
  float* nhs = (float*)(smraw + 49152);                   // 256 floats

  const int tid = threadIdx.x;
  const int lane = tid & 63;
  const int wv = tid >> 6;
  const int rg = blockIdx.x & (SC_RG - 1);
  const int ch = blockIdx.x >> 7;
  const int rowbase = rg * 256;
  const int m = lane & 15, q = lane >> 4;

  {  // phase 1: stage 256 target rows
    const float4* src = (const float4*)(targets + (size_t)(rowbase + tid) * CB);
    float4 a = src[0], b = src[1], c = src[2], d = src[3];
    *(float4*)&tst[tid * 20 + 0] = a;
    *(float4*)&tst[tid * 20 + 4] = b;
    *(float4*)&tst[tid * 20 + 8] = c;
    *(float4*)&tst[tid * 20 + 12] = d;
  }
  __syncthreads();

  // phase 2: A-frags. A12=[t1|t2], A13=[t1|t3]; lane quad q holds k=q*8+j.
  bf16x8 A12[4], A13[4];
#pragma unroll
  for (int rt = 0; rt < 4; rt++) {
    int row = wv * 64 + rt * 16 + m;
    const float* tp = &tst[row * 20 + (q & 1) * 8];
    float4 u0 = *(const float4*)tp;
    float4 u1 = *(const float4*)(tp + 4);
    float te[8] = {u0.x, u0.y, u0.z, u0.w, u1.x, u1.y, u1.z, u1.w};
    bf16x8 v12, v13;
#pragma unroll
    for (int j = 0; j < 8; j++) {
      unsigned short a = bf16rn(te[j]);
      float r1 = te[j] - bf16tof(a);
      unsigned short b = bf16rn(r1);
      float r2 = r1 - bf16tof(b);
      unsigned short c = bf16rn(r2);
      v12[j] = (short)((q < 2) ? a : b);
      v13[j] = (short)((q < 2) ? a : c);
    }
    A12[rt] = v12;
    A13[rt] = v13;
  }

  float s1[4][4], s2[4][4];
  int i1[4][4];
#pragma unroll
  for (int rt = 0; rt < 4; rt++)
#pragma unroll
    for (int r = 0; r < 4; r++) { s1[rt][r] = -3.4e38f; s2[rt][r] = -3.4e38f; i1[rt][r] = 0; }

  for (int sc = 0; sc < 4; sc++) {
    const int jb = ch * 1024 + sc * 256;
    __syncthreads();  // prior sweep reads (or phase-2 tst reads) done before bfr overwrite
    {  // stage 256 books as B-frags + nh
      int bt = tid >> 4, n = tid & 15;
      const float4* src = (const float4*)(codebook + (size_t)(jb + tid) * CB);
      float4 a = src[0], b = src[1], c = src[2], d = src[3];
      float ce[16] = {a.x, a.y, a.z, a.w, b.x, b.y, b.z, b.w,
                      c.x, c.y, c.z, c.w, d.x, d.y, d.z, d.w};
      short c1[16], c2[16], c3[16];
      double s = 0.0;
#pragma unroll
      for (int j = 0; j < 16; j++) {
        s += (double)ce[j] * (double)ce[j];
        unsigned short x1 = bf16rn(ce[j]);
        float r1 = ce[j] - bf16tof(x1);
        unsigned short x2 = bf16rn(r1);
        float r2 = r1 - bf16tof(x2);
        unsigned short x3 = bf16rn(r2);
        c1[j] = (short)x1; c2[j] = (short)x2; c3[j] = (short)x3;
      }
      nhs[tid] = (float)(-0.5 * s);
      bf16x8 lo1, hi1, lo2, hi2, lo3, hi3;
#pragma unroll
      for (int j = 0; j < 8; j++) {
        lo1[j] = c1[j]; hi1[j] = c1[j + 8];
        lo2[j] = c2[j]; hi2[j] = c2[j + 8];
        lo3[j] = c3[j]; hi3[j] = c3[j + 8];
      }
      *(bf16x8*)bfr[0][bt][0 * 16 + n] = lo1;
      *(bf16x8*)bfr[0][bt][1 * 16 + n] = hi1;
      *(bf16x8*)bfr[0][bt][2 * 16 + n] = lo1;
      *(bf16x8*)bfr[0][bt][3 * 16 + n] = hi1;
      *(bf16x8*)bfr[1][bt][0 * 16 + n] = lo2;
      *(bf16x8*)bfr[1][bt][1 * 16 + n] = hi2;
      *(bf16x8*)bfr[1][bt][2 * 16 + n] = lo2;
      *(bf16x8*)bfr[1][bt][3 * 16 + n] = hi2;
      *(bf16x8*)bfr[2][bt][0 * 16 + n] = lo3;
      *(bf16x8*)bfr[2][bt][1 * 16 + n] = hi3;
      *(bf16x8*)bfr[2][bt][2 * 16 + n] = lo1;
      *(bf16x8*)bfr[2][bt][3 * 16 + n] = hi1;
    }
    __syncthreads();

    for (int bt = 0; bt < 16; bt++) {
      bf16x8 b1 = *(const bf16x8*)bfr[0][bt][lane];
      bf16x8 b2 = *(const bf16x8*)bfr[1][bt][lane];
      bf16x8 b3 = *(const bf16x8*)bfr[2][bt][lane];
      float nhv = nhs[bt * 16 + m];
      int colid = jb + bt * 16 + m;
#pragma unroll
      for (int rt = 0; rt < 4; rt++) {
        f32x4 acc = {0.f, 0.f, 0.f, 0.f};
        acc = MFMA(A12[rt], b1, acc, 0, 0, 0);
        acc = MFMA(A12[rt], b2, acc, 0, 0, 0);
        acc = MFMA(A13[rt], b3, acc, 0, 0, 0);
#pragma unroll
        for (int r = 0; r < 4; r++) {
          float mv = acc[r] + nhv;
          bool g = mv > s1[rt][r];
          s2[rt][r] = g ? s1[rt][r] : fmaxf(s2[rt][r], mv);
          i1[rt][r] = g ? colid : i1[rt][r];
          s1[rt][r] = fmaxf(s1[rt][r], mv);
        }
      }
    }
  }

  // cross-lane top-2 merge over the 16 column-lanes (ties -> min index)
#pragma unroll
  for (int rt = 0; rt < 4; rt++)
#pragma unroll
    for (int r = 0; r < 4; r++) {
      float a1v = s1[rt][r], a2v = s2[rt][r];
      int ai = i1[rt][r];
#pragma unroll
      for (int msk = 1; msk <= 8; msk <<= 1) {
        float o1 = __shfl_xor(a1v, msk);
        float o2 = __shfl_xor(a2v, msk);
        int oi = __shfl_xor(ai, msk);
        if (o1 > a1v) {
          a2v = fmaxf(a1v, o2); a1v = o1; ai = oi;
        } else {
          a2v = fmaxf(a2v, o1);
          if (o1 == a1v && oi < ai) ai = oi;
        }
      }
      if (m == 0) {
        int row = rowbase + wv * 64 + rt * 16 + q * 4 + r;
        cand[(size_t)ch * N_ROWS + row] = make_float4(a1v, a2v, __int_as_float(ai), 0.f);
      }
    }
}

// ---------------- Kernel 3: merge chunks; write label + near-tie flag ----------------
#define MARGIN_EPS 2.0e-3f

__global__ __launch_bounds__(256) void reduce_kernel(const float4* __restrict__ cand,
                                                     int* __restrict__ out,
                                                     int* __restrict__ flags) {
  int r = blockIdx.x * 256 + threadIdx.x;
  float S1 = -3.4e38f, S2 = -3.4e38f;
  int I = 0;
#pragma unroll
  for (int ch = 0; ch < SC_NCH; ch++) {  // ascending: strict '>' keeps first index
    float4 v = cand[(size_t)ch * N_ROWS + r];
    if (v.x > S1) {
      S2 = fmaxf(S1, v.y); S1 = v.x; I = __float_as_int(v.z);
    } else {
      S2 = fmaxf(S2, v.x);
    }
  }
  out[r] = I;
  flags[r] = (S1 - S2 < MARGIN_EPS) ? 1 : 0;
}

// ---------------- Kernel 4: exact fp64 rescore of flagged rows ----------------
__global__ __launch_bounds__(256) void fallback_kernel(const float* __restrict__ targets,
                                                       const float* __restrict__ codebook,
                                                       const int* __restrict__ flags,
                                                       int* __restrict__ out) {
  __shared__ int fcache[128];
  __shared__ double rs[256];
  __shared__ int ri[256];
  const int tid = threadIdx.x;
  const int base = blockIdx.x * 128;
  if (tid < 128) fcache[tid] = flags[base + tid];
  __syncthreads();

  for (int rr = 0; rr < 128; rr++) {
    if (!fcache[rr]) continue;  // block-uniform
    const int row = base + rr;
    double t[16];
#pragma unroll
    for (int i = 0; i < 16; i++) t[i] = (double)targets[(size_t)row * CB + i];
    double bs = -1.0e300;
    int bi = 0;
    for (int j = tid; j < N_BOOKS; j += 256) {
      const float* cp = codebook + (size_t)j * CB;
      double dot = 0.0, cc = 0.0;
#pragma unroll
      for (int i = 0; i < 16; i++) {
        double cv = (double)cp[i];
        dot = fma(t[i], cv, dot);
        cc = fma(cv, cv, cc);
      }
      double mv = dot - 0.5 * cc;
      if (mv > bs) { bs = mv; bi = j; }  // ascending j: first wins
    }
    rs[tid] = bs; ri[tid] = bi;
    __syncthreads();
    for (int s = 128; s > 0; s >>= 1) {
      if (tid < s) {
        double os = rs[tid + s]; int oi = ri[tid + s];
        if (os > rs[tid] || (os == rs[tid] && oi < ri[tid])) { rs[tid] = os; ri[tid] = oi; }
      }
      __syncthreads();
    }
    if (tid == 0) out[row] = ri[0];
    __syncthreads();
  }
}

extern "C" void kernel_launch(void* const* d_in, const int* in_sizes, int n_in,
                              void* d_out, int out_size, void* d_ws, size_t ws_size,
                              hipStream_t stream) {
  (void)in_sizes; (void)n_in; (void)out_size; (void)ws_size;
  const float* x = (const float*)d_in[0];
  // d_in[1] = mask_time_indices: all-ones -> flatten; unused
  const float* w = (const float*)d_in[2];
  const float* codebook = (const float*)d_in[3];

  char* ws = (char*)d_ws;
  float* targets = (float*)ws;                                   // 2 MB
  float4* cand = (float4*)(ws + 2 * 1024 * 1024);                // 8ch x 32768 x 16B = 4 MB
  int* flags = (int*)(ws + 6 * 1024 * 1024);                     // 128 KB
  int* out = (int*)d_out;

  proj_kernel<<<N_ROWS / 64, 256, 0, stream>>>(x, w, targets);
  score_kernel<<<SC_RG * SC_NCH, 256, 0, stream>>>(targets, codebook, cand);
  reduce_kernel<<<N_ROWS / 256, 256, 0, stream>>>(cand, out, flags);
  fallback_kernel<<<N_ROWS / 128, 256, 0, stream>>>(targets, codebook, flags, out);
}